// Round 7
// baseline (177.284 us; speedup 1.0000x reference)
//
#include <hip/hip_runtime.h>
#include <math.h>

#define NPTS 200
#define NCH  13
#define BLK  256
#define FLT_PER_BATCH (NPTS * NCH)          // 2600

// 4-byte-aligned float4 for dword-aligned (not 16B-aligned) vector loads
typedef float f4u __attribute__((ext_vector_type(4), aligned(4)));

// ---------------------------------------------------------------------------
// Single fused kernel. One batch per wave (4 batches/block).
//   phase 1: direct-global weighted reduction, xyz2 kept in registers
//   phase 2: block solve — lanes 0-3 of wave 0 solve 4 batches SIMT
//   phase 3: apply R,t from registers; stores staged through LDS as float4
// Two __syncthreads total; no global scratch; one launch.
// ---------------------------------------------------------------------------
__global__ __launch_bounds__(BLK, 4) void svd_align_fused(
    const float* __restrict__ net_in,   // (B, 200, 13)
    const float* __restrict__ shift_p,
    const float* __restrict__ a_p,
    const float* __restrict__ b_p,
    float* __restrict__ out)            // (B, 200, 3)
{
    __shared__ float s_part[4][16][20];   // per-wave 16x16 transpose (5.1 KB)
    __shared__ float s_sums[4][16];       // per-batch totals          (256 B)
    __shared__ float s_Rt[4][12];         // per-batch R,t             (192 B)
    __shared__ float s_out[4][NPTS * 3];  // per-wave store staging    (9.6 KB)

    const int tid = threadIdx.x;
    const int w   = tid >> 6;             // wave id = local batch
    const int l   = tid & 63;
    const int b   = blockIdx.x * 4 + w;   // global batch

    const float shift = shift_p[0];
    const float aa    = a_p[0];
    const float bb    = b_p[0];

    const float* base = net_in + (size_t)b * FLT_PER_BATCH;

    // ---- phase 1: direct-global reduce; keep xyz2 in registers ----
    float acc[16];
    #pragma unroll
    for (int k = 0; k < 16; ++k) acc[k] = 0.f;

    float rx[4], ry[4], rz[4];

    #pragma unroll
    for (int j = 0; j < 4; ++j) {
        const int p = l + 64 * j;         // j<3 always valid; j==3 only l<8
        if (j < 3 || l < 8) {
            const float* q = base + p * NCH;
            const f4u q0 = *(const f4u*)(q);      // w,  x1, y1, z1
            const f4u q1 = *(const f4u*)(q + 4);  // x2, y2, z2, n1x
            const f4u q2 = *(const f4u*)(q + 8);  // n1y,n1z,n2x, n2y
            const float qs = q[12];               // n2z

            float wt = aa * q0.x + bb;
            wt = fmaxf(wt, 0.f) + 1e-8f;
            rx[j] = q1.x; ry[j] = q1.y; rz[j] = q1.z;
            const float v1x = fmaf(shift, q1.w, q0.y);
            const float v1y = fmaf(shift, q2.x, q0.z);
            const float v1z = fmaf(shift, q2.y, q0.w);
            const float v2x = fmaf(shift, q2.z, q1.x);
            const float v2y = fmaf(shift, q2.w, q1.y);
            const float v2z = fmaf(shift, qs,   q1.z);
            const float wv2x = wt * v2x, wv2y = wt * v2y, wv2z = wt * v2z;
            acc[0] += wt;
            acc[1] += wt * v1x; acc[2] += wt * v1y; acc[3] += wt * v1z;
            acc[4] += wv2x;     acc[5] += wv2y;     acc[6] += wv2z;
            acc[7]  += wv2x * v1x; acc[8]  += wv2x * v1y; acc[9]  += wv2x * v1z;
            acc[10] += wv2y * v1x; acc[11] += wv2y * v1y; acc[12] += wv2y * v1z;
            acc[13] += wv2z * v1x; acc[14] += wv2z * v1y; acc[15] += wv2z * v1z;
        } else {
            rx[j] = 0.f; ry[j] = 0.f; rz[j] = 0.f;
        }
    }

    // 64 -> 16 lanes
    #pragma unroll
    for (int k = 0; k < 16; ++k) {
        acc[k] += __shfl_down(acc[k], 32, 64);
        acc[k] += __shfl_down(acc[k], 16, 64);
    }
    // 16x16 transpose in wave-private LDS (same wave: no barrier)
    if (l < 16) {
        float4* pp = (float4*)&s_part[w][l][0];
        pp[0] = make_float4(acc[0],  acc[1],  acc[2],  acc[3]);
        pp[1] = make_float4(acc[4],  acc[5],  acc[6],  acc[7]);
        pp[2] = make_float4(acc[8],  acc[9],  acc[10], acc[11]);
        pp[3] = make_float4(acc[12], acc[13], acc[14], acc[15]);
    }
    if (l < 16) {
        float s = 0.f;
        #pragma unroll
        for (int r = 0; r < 16; ++r) s += s_part[w][r][l];
        s_sums[w][l] = s;
    }
    __syncthreads();

    // ---- phase 2: lanes 0-3 of wave 0 solve the block's 4 batches SIMT ----
    if (tid < 4) {
        float f[16];
        #pragma unroll
        for (int k = 0; k < 16; ++k) f[k] = s_sums[tid][k];

        const float W = f[0];
        const float invW = 1.0f / W;
        const float v1cx = f[1] * invW, v1cy = f[2] * invW, v1cz = f[3] * invW;
        const float v2cx = f[4] * invW, v2cy = f[5] * invW, v2cz = f[6] * invW;

        const float Sxx = f[7]  - W * v2cx * v1cx;
        const float Sxy = f[8]  - W * v2cx * v1cy;
        const float Sxz = f[9]  - W * v2cx * v1cz;
        const float Syx = f[10] - W * v2cy * v1cx;
        const float Syy = f[11] - W * v2cy * v1cy;
        const float Syz = f[12] - W * v2cy * v1cz;
        const float Szx = f[13] - W * v2cz * v1cx;
        const float Szy = f[14] - W * v2cz * v1cy;
        const float Szz = f[15] - W * v2cz * v1cz;

        float A[4][4];
        A[0][0] = Sxx + Syy + Szz;
        A[0][1] = Syz - Szy;  A[0][2] = Szx - Sxz;  A[0][3] = Sxy - Syx;
        A[1][1] = Sxx - Syy - Szz;
        A[1][2] = Sxy + Syx;  A[1][3] = Szx + Sxz;
        A[2][2] = -Sxx + Syy - Szz;
        A[2][3] = Syz + Szy;
        A[3][3] = -Sxx - Syy + Szz;
        A[1][0] = A[0][1]; A[2][0] = A[0][2]; A[3][0] = A[0][3];
        A[2][1] = A[1][2]; A[3][1] = A[1][3]; A[3][2] = A[2][3];

        float V[4][4] = {{1,0,0,0},{0,1,0,0},{0,0,1,0},{0,0,0,1}};

        const int prs[6][2] = {{0,1},{0,2},{0,3},{1,2},{1,3},{2,3}};
        for (int sweep = 0; sweep < 6; ++sweep) {
            #pragma unroll
            for (int r = 0; r < 6; ++r) {
                const int p = prs[r][0], q = prs[r][1];
                float apq = A[p][q];
                if (apq != 0.0f) {
                    float tau = (A[q][q] - A[p][p]) / (2.0f * apq);
                    float t = copysignf(1.0f, tau) /
                              (fabsf(tau) + sqrtf(1.0f + tau * tau));
                    float c = rsqrtf(1.0f + t * t);
                    float s = t * c;
                    #pragma unroll
                    for (int k = 0; k < 4; ++k) {
                        float a1 = A[p][k], a2 = A[q][k];
                        A[p][k] = c * a1 - s * a2;
                        A[q][k] = s * a1 + c * a2;
                    }
                    #pragma unroll
                    for (int k = 0; k < 4; ++k) {
                        float a1 = A[k][p], a2 = A[k][q];
                        A[k][p] = c * a1 - s * a2;
                        A[k][q] = s * a1 + c * a2;
                    }
                    #pragma unroll
                    for (int k = 0; k < 4; ++k) {
                        float a1 = V[k][p], a2 = V[k][q];
                        V[k][p] = c * a1 - s * a2;
                        V[k][q] = s * a1 + c * a2;
                    }
                }
            }
        }

        int best = 0;
        #pragma unroll
        for (int i = 1; i < 4; ++i) if (A[i][i] > A[best][best]) best = i;
        const float q0 = V[0][best], qx = V[1][best], qy = V[2][best], qz = V[3][best];

        const float R00 = q0*q0 + qx*qx - qy*qy - qz*qz;
        const float R01 = 2.0f * (qx*qy - q0*qz);
        const float R02 = 2.0f * (qx*qz + q0*qy);
        const float R10 = 2.0f * (qx*qy + q0*qz);
        const float R11 = q0*q0 - qx*qx + qy*qy - qz*qz;
        const float R12 = 2.0f * (qy*qz - q0*qx);
        const float R20 = 2.0f * (qx*qz - q0*qy);
        const float R21 = 2.0f * (qy*qz + q0*qx);
        const float R22 = q0*q0 - qx*qx - qy*qy + qz*qz;

        s_Rt[tid][0]  = R00; s_Rt[tid][1]  = R01; s_Rt[tid][2]  = R02;
        s_Rt[tid][3]  = R10; s_Rt[tid][4]  = R11; s_Rt[tid][5]  = R12;
        s_Rt[tid][6]  = R20; s_Rt[tid][7]  = R21; s_Rt[tid][8]  = R22;
        s_Rt[tid][9]  = v1cx - (R00 * v2cx + R01 * v2cy + R02 * v2cz);
        s_Rt[tid][10] = v1cy - (R10 * v2cx + R11 * v2cy + R12 * v2cz);
        s_Rt[tid][11] = v1cz - (R20 * v2cx + R21 * v2cy + R22 * v2cz);
    }
    __syncthreads();

    // ---- phase 3: apply from registers, stage to LDS, float4 store ----
    const float R00 = s_Rt[w][0], R01 = s_Rt[w][1], R02 = s_Rt[w][2];
    const float R10 = s_Rt[w][3], R11 = s_Rt[w][4], R12 = s_Rt[w][5];
    const float R20 = s_Rt[w][6], R21 = s_Rt[w][7], R22 = s_Rt[w][8];
    const float t0  = s_Rt[w][9], t1  = s_Rt[w][10], t2 = s_Rt[w][11];

    float* so = s_out[w];
    #pragma unroll
    for (int j = 0; j < 4; ++j) {
        const int p = l + 64 * j;
        if (j < 3 || l < 8) {
            const float x = rx[j], y = ry[j], z = rz[j];
            so[p * 3 + 0] = R00 * x + R01 * y + R02 * z + t0;   // stride-3: 2-way
            so[p * 3 + 1] = R10 * x + R11 * y + R12 * z + t1;   // bank alias = free
            so[p * 3 + 2] = R20 * x + R21 * y + R22 * z + t2;
        }
    }
    // wave-synchronous readback as float4, fully coalesced global store
    {
        float4* ob = (float4*)(out + (size_t)b * (NPTS * 3));
        const float4* sv = (const float4*)so;
        ob[l]      = sv[l];           // 150 float4 per batch
        ob[64 + l] = sv[64 + l];
        if (l < 22) ob[128 + l] = sv[128 + l];
    }
}

extern "C" void kernel_launch(void* const* d_in, const int* in_sizes, int n_in,
                              void* d_out, int out_size, void* d_ws, size_t ws_size,
                              hipStream_t stream) {
    const float* net_in  = (const float*)d_in[0];
    const float* shift_p = (const float*)d_in[1];
    const float* a_p     = (const float*)d_in[2];
    const float* b_p     = (const float*)d_in[3];
    float* out = (float*)d_out;

    const int B = in_sizes[0] / FLT_PER_BATCH;   // 8192

    svd_align_fused<<<B / 4, BLK, 0, stream>>>(net_in, shift_p, a_p, b_p, out);
}

// Round 8
// 171.759 us; speedup vs baseline: 1.0322x; 1.0322x over previous
//
#include <hip/hip_runtime.h>
#include <math.h>

#define NPTS 200
#define NCH  13
#define BLK  256
#define FLT_PER_BATCH (NPTS * NCH)          // 2600

// 4-byte-aligned float4 for dword-aligned (not 16B-aligned) vector loads
typedef float f4u __attribute__((ext_vector_type(4), aligned(4)));

// ---------------------------------------------------------------------------
// Kernel 1: reduce2 — TWO waves per batch (wave h handles points
// h*100 .. h*100+99), direct strided global loads, one barrier, 16x16 LDS
// transpose combine across the wave pair. 2 batches per 256-thread block.
// ---------------------------------------------------------------------------
__global__ __launch_bounds__(BLK) void reduce2_kernel(
    const float* __restrict__ net_in,   // (B, 200, 13)
    const float* __restrict__ shift_p,
    const float* __restrict__ a_p,
    const float* __restrict__ b_p,
    float* __restrict__ sums)           // (B, 16)
{
    __shared__ float s_part[4][16][20];       // per-wave 16x16 transpose (5.1 KB)

    const int tid = threadIdx.x;
    const int w   = tid >> 6;                 // wave 0..3
    const int l   = tid & 63;
    const int b   = blockIdx.x * 2 + (w >> 1);  // global batch
    const int h   = w & 1;                      // half: points h*100..h*100+99

    const float shift = shift_p[0];
    const float aa    = a_p[0];
    const float bb    = b_p[0];

    const float* base = net_in + (size_t)b * FLT_PER_BATCH;

    float acc[16];
    #pragma unroll
    for (int k = 0; k < 16; ++k) acc[k] = 0.f;

    #pragma unroll
    for (int j = 0; j < 2; ++j) {
        const int p = h * 100 + l + 64 * j;   // j=0: all lanes; j=1: l<36
        if (j == 0 || l < 36) {
            const float* q = base + p * NCH;
            const f4u q0 = *(const f4u*)(q);      // w,  x1, y1, z1
            const f4u q1 = *(const f4u*)(q + 4);  // x2, y2, z2, n1x
            const f4u q2 = *(const f4u*)(q + 8);  // n1y,n1z,n2x, n2y
            const float qs = q[12];               // n2z

            float wt = aa * q0.x + bb;
            wt = fmaxf(wt, 0.f) + 1e-8f;
            const float v1x = fmaf(shift, q1.w, q0.y);
            const float v1y = fmaf(shift, q2.x, q0.z);
            const float v1z = fmaf(shift, q2.y, q0.w);
            const float v2x = fmaf(shift, q2.z, q1.x);
            const float v2y = fmaf(shift, q2.w, q1.y);
            const float v2z = fmaf(shift, qs,   q1.z);
            const float wv2x = wt * v2x, wv2y = wt * v2y, wv2z = wt * v2z;
            acc[0] += wt;
            acc[1] += wt * v1x; acc[2] += wt * v1y; acc[3] += wt * v1z;
            acc[4] += wv2x;     acc[5] += wv2y;     acc[6] += wv2z;
            acc[7]  += wv2x * v1x; acc[8]  += wv2x * v1y; acc[9]  += wv2x * v1z;
            acc[10] += wv2y * v1x; acc[11] += wv2y * v1y; acc[12] += wv2y * v1z;
            acc[13] += wv2z * v1x; acc[14] += wv2z * v1y; acc[15] += wv2z * v1z;
        }
    }

    // ---- 64 -> 16 lanes via 2 shuffle levels ----
    #pragma unroll
    for (int k = 0; k < 16; ++k) {
        acc[k] += __shfl_down(acc[k], 32, 64);
        acc[k] += __shfl_down(acc[k], 16, 64);
    }

    // ---- per-wave 16x16 transpose into LDS ----
    if (l < 16) {
        float4* pp = (float4*)&s_part[w][l][0];
        pp[0] = make_float4(acc[0],  acc[1],  acc[2],  acc[3]);
        pp[1] = make_float4(acc[4],  acc[5],  acc[6],  acc[7]);
        pp[2] = make_float4(acc[8],  acc[9],  acc[10], acc[11]);
        pp[3] = make_float4(acc[12], acc[13], acc[14], acc[15]);
    }
    __syncthreads();

    // ---- even waves combine the pair and store ----
    if (h == 0 && l < 16) {
        float s = 0.f;
        #pragma unroll
        for (int r = 0; r < 16; ++r) s += s_part[w][r][l] + s_part[w + 1][r][l];
        sums[(size_t)b * 16 + l] = s;
    }
}

// ---------------------------------------------------------------------------
// Kernel 2: solve (lanes 0-3 of wave 0, SIMT, 5 sweeps) + apply (one wave
// per batch, xyz2 from L3-hot net_in, LDS-staged float4 stores).
// ---------------------------------------------------------------------------
__global__ __launch_bounds__(BLK) void solve_apply_kernel(
    const float* __restrict__ net_in,   // (B, 200, 13)
    const float* __restrict__ sums,     // (B, 16)
    float* __restrict__ out)            // (B, 200, 3)
{
    __shared__ float s_Rt[4][12];
    __shared__ float s_out[4][NPTS * 3];   // 9.6 KB

    const int tid = threadIdx.x;
    const int w   = tid >> 6;
    const int l   = tid & 63;
    const int b0  = blockIdx.x * 4;
    const int b   = b0 + w;

    // ---- phase 1: lanes 0-3 solve the block's 4 batches SIMT ----
    if (tid < 4) {
        float f[16];
        #pragma unroll
        for (int k = 0; k < 16; ++k) f[k] = sums[(size_t)(b0 + tid) * 16 + k];

        const float W = f[0];
        const float invW = 1.0f / W;
        const float v1cx = f[1] * invW, v1cy = f[2] * invW, v1cz = f[3] * invW;
        const float v2cx = f[4] * invW, v2cy = f[5] * invW, v2cz = f[6] * invW;

        const float Sxx = f[7]  - W * v2cx * v1cx;
        const float Sxy = f[8]  - W * v2cx * v1cy;
        const float Sxz = f[9]  - W * v2cx * v1cz;
        const float Syx = f[10] - W * v2cy * v1cx;
        const float Syy = f[11] - W * v2cy * v1cy;
        const float Syz = f[12] - W * v2cy * v1cz;
        const float Szx = f[13] - W * v2cz * v1cx;
        const float Szy = f[14] - W * v2cz * v1cy;
        const float Szz = f[15] - W * v2cz * v1cz;

        float A[4][4];
        A[0][0] = Sxx + Syy + Szz;
        A[0][1] = Syz - Szy;  A[0][2] = Szx - Sxz;  A[0][3] = Sxy - Syx;
        A[1][1] = Sxx - Syy - Szz;
        A[1][2] = Sxy + Syx;  A[1][3] = Szx + Sxz;
        A[2][2] = -Sxx + Syy - Szz;
        A[2][3] = Syz + Szy;
        A[3][3] = -Sxx - Syy + Szz;
        A[1][0] = A[0][1]; A[2][0] = A[0][2]; A[3][0] = A[0][3];
        A[2][1] = A[1][2]; A[3][1] = A[1][3]; A[3][2] = A[2][3];

        float V[4][4] = {{1,0,0,0},{0,1,0,0},{0,0,1,0},{0,0,0,1}};

        const int prs[6][2] = {{0,1},{0,2},{0,3},{1,2},{1,3},{2,3}};
        for (int sweep = 0; sweep < 5; ++sweep) {
            #pragma unroll
            for (int r = 0; r < 6; ++r) {
                const int p = prs[r][0], q = prs[r][1];
                float apq = A[p][q];
                if (apq != 0.0f) {
                    float tau = (A[q][q] - A[p][p]) / (2.0f * apq);
                    float t = copysignf(1.0f, tau) /
                              (fabsf(tau) + sqrtf(1.0f + tau * tau));
                    float c = rsqrtf(1.0f + t * t);
                    float s = t * c;
                    #pragma unroll
                    for (int k = 0; k < 4; ++k) {
                        float a1 = A[p][k], a2 = A[q][k];
                        A[p][k] = c * a1 - s * a2;
                        A[q][k] = s * a1 + c * a2;
                    }
                    #pragma unroll
                    for (int k = 0; k < 4; ++k) {
                        float a1 = A[k][p], a2 = A[k][q];
                        A[k][p] = c * a1 - s * a2;
                        A[k][q] = s * a1 + c * a2;
                    }
                    #pragma unroll
                    for (int k = 0; k < 4; ++k) {
                        float a1 = V[k][p], a2 = V[k][q];
                        V[k][p] = c * a1 - s * a2;
                        V[k][q] = s * a1 + c * a2;
                    }
                }
            }
        }

        int best = 0;
        #pragma unroll
        for (int i = 1; i < 4; ++i) if (A[i][i] > A[best][best]) best = i;
        const float q0 = V[0][best], qx = V[1][best], qy = V[2][best], qz = V[3][best];

        const float R00 = q0*q0 + qx*qx - qy*qy - qz*qz;
        const float R01 = 2.0f * (qx*qy - q0*qz);
        const float R02 = 2.0f * (qx*qz + q0*qy);
        const float R10 = 2.0f * (qx*qy + q0*qz);
        const float R11 = q0*q0 - qx*qx + qy*qy - qz*qz;
        const float R12 = 2.0f * (qy*qz - q0*qx);
        const float R20 = 2.0f * (qx*qz - q0*qy);
        const float R21 = 2.0f * (qy*qz + q0*qx);
        const float R22 = q0*q0 - qx*qx - qy*qy + qz*qz;

        s_Rt[tid][0]  = R00; s_Rt[tid][1]  = R01; s_Rt[tid][2]  = R02;
        s_Rt[tid][3]  = R10; s_Rt[tid][4]  = R11; s_Rt[tid][5]  = R12;
        s_Rt[tid][6]  = R20; s_Rt[tid][7]  = R21; s_Rt[tid][8]  = R22;
        s_Rt[tid][9]  = v1cx - (R00 * v2cx + R01 * v2cy + R02 * v2cz);
        s_Rt[tid][10] = v1cy - (R10 * v2cx + R11 * v2cy + R12 * v2cz);
        s_Rt[tid][11] = v1cz - (R20 * v2cx + R21 * v2cy + R22 * v2cz);
    }
    __syncthreads();

    // ---- phase 2: wave w applies batch b0+w ----
    const float R00 = s_Rt[w][0], R01 = s_Rt[w][1], R02 = s_Rt[w][2];
    const float R10 = s_Rt[w][3], R11 = s_Rt[w][4], R12 = s_Rt[w][5];
    const float R20 = s_Rt[w][6], R21 = s_Rt[w][7], R22 = s_Rt[w][8];
    const float t0  = s_Rt[w][9], t1  = s_Rt[w][10], t2 = s_Rt[w][11];

    const float* base = net_in + (size_t)b * FLT_PER_BATCH;
    float* so = s_out[w];
    #pragma unroll
    for (int j = 0; j < 4; ++j) {
        const int p = l + 64 * j;
        if (j < 3 || l < 8) {
            const f4u v = *(const f4u*)(base + p * NCH + 4);   // x2,y2,z2,(n1x)
            so[p * 3 + 0] = R00 * v.x + R01 * v.y + R02 * v.z + t0;
            so[p * 3 + 1] = R10 * v.x + R11 * v.y + R12 * v.z + t1;
            so[p * 3 + 2] = R20 * v.x + R21 * v.y + R22 * v.z + t2;
        }
    }
    // wave-synchronous readback, fully coalesced float4 stores
    {
        float4* ob = (float4*)(out + (size_t)b * (NPTS * 3));
        const float4* sv = (const float4*)so;
        ob[l]      = sv[l];
        ob[64 + l] = sv[64 + l];
        if (l < 22) ob[128 + l] = sv[128 + l];
    }
}

extern "C" void kernel_launch(void* const* d_in, const int* in_sizes, int n_in,
                              void* d_out, int out_size, void* d_ws, size_t ws_size,
                              hipStream_t stream) {
    const float* net_in  = (const float*)d_in[0];
    const float* shift_p = (const float*)d_in[1];
    const float* a_p     = (const float*)d_in[2];
    const float* b_p     = (const float*)d_in[3];
    float* out = (float*)d_out;

    const int B = in_sizes[0] / FLT_PER_BATCH;   // 8192

    float* sums = (float*)d_ws;                  // B * 16 floats

    reduce2_kernel<<<B / 2, BLK, 0, stream>>>(net_in, shift_p, a_p, b_p, sums);
    solve_apply_kernel<<<B / 4, BLK, 0, stream>>>(net_in, sums, out);
}

// Round 9
// 162.220 us; speedup vs baseline: 1.0929x; 1.0588x over previous
//
#include <hip/hip_runtime.h>
#include <math.h>

#define NPTS 200
#define NCH  13
#define BLK  256
#define FPB  (NPTS * NCH)          // 2600 floats per batch

// 4-byte-aligned float4 for dword-aligned (not 16B-aligned) vector loads
typedef float f4u __attribute__((ext_vector_type(4), aligned(4)));

// ---------------------------------------------------------------------------
// Kernel 1: reduce — one wave per batch, async global->LDS staging via
// global_load_lds (width=16, no data VGPRs: ~10.4 KB in flight per wave),
// wave-private LDS, ZERO __syncthreads. 16 weighted sums per batch.
// ---------------------------------------------------------------------------
__global__ __launch_bounds__(BLK) void reduce_kernel(
    const float* __restrict__ net_in,   // (B, 200, 13)
    const float* __restrict__ shift_p,
    const float* __restrict__ a_p,
    const float* __restrict__ b_p,
    float* __restrict__ sums)           // (B, 16)
{
    __shared__ float s_in[4 * FPB];       // 4 waves * 2600 floats (41.6 KB)
    __shared__ float s_part[4][16][20];   // per-wave 16x16 transpose (5.1 KB)

    const int tid = threadIdx.x;
    const int w   = tid >> 6;             // wave id = local batch
    const int l   = tid & 63;
    const int b   = blockIdx.x * 4 + w;   // global batch

    const float shift = shift_p[0];
    const float aa    = a_p[0];
    const float bb    = b_p[0];

    const float* src = net_in + (size_t)b * FPB;
    float*       dst = s_in + w * FPB;    // wave-private LDS region

    // ---- async stage: 650 float4; LDS dest = wave-uniform base + lane*16B ----
    #pragma unroll
    for (int j = 0; j < 10; ++j) {
        __builtin_amdgcn_global_load_lds(
            (const __attribute__((address_space(1))) void*)(src + j * 256 + l * 4),
            (__attribute__((address_space(3))) void*)(dst + j * 256),
            16, 0, 0);
    }
    if (l < 10) {
        __builtin_amdgcn_global_load_lds(
            (const __attribute__((address_space(1))) void*)(src + 2560 + l * 4),
            (__attribute__((address_space(3))) void*)(dst + 2560),
            16, 0, 0);
    }
    __builtin_amdgcn_s_waitcnt(0);        // drain this wave's staging queue
    __asm__ __volatile__("" ::: "memory");  // keep LDS reads below the wait

    // ---- per-lane accumulation over 3-4 points (52B stride: 2-way = free) ----
    float acc[16];
    #pragma unroll
    for (int k = 0; k < 16; ++k) acc[k] = 0.f;

    #pragma unroll
    for (int j = 0; j < 4; ++j) {
        const int p = l + 64 * j;         // j<3 always valid; j==3 only l<8
        if (j < 3 || l < 8) {
            const float* q = dst + p * NCH;
            float wt = aa * q[0] + bb;
            wt = fmaxf(wt, 0.f) + 1e-8f;
            const float v1x = fmaf(shift, q[7],  q[1]);
            const float v1y = fmaf(shift, q[8],  q[2]);
            const float v1z = fmaf(shift, q[9],  q[3]);
            const float v2x = fmaf(shift, q[10], q[4]);
            const float v2y = fmaf(shift, q[11], q[5]);
            const float v2z = fmaf(shift, q[12], q[6]);
            const float wv2x = wt * v2x, wv2y = wt * v2y, wv2z = wt * v2z;
            acc[0] += wt;
            acc[1] += wt * v1x; acc[2] += wt * v1y; acc[3] += wt * v1z;
            acc[4] += wv2x;     acc[5] += wv2y;     acc[6] += wv2z;
            acc[7]  += wv2x * v1x; acc[8]  += wv2x * v1y; acc[9]  += wv2x * v1z;
            acc[10] += wv2y * v1x; acc[11] += wv2y * v1y; acc[12] += wv2y * v1z;
            acc[13] += wv2z * v1x; acc[14] += wv2z * v1y; acc[15] += wv2z * v1z;
        }
    }

    // ---- 64 -> 16 lanes via 2 shuffle levels ----
    #pragma unroll
    for (int k = 0; k < 16; ++k) {
        acc[k] += __shfl_down(acc[k], 32, 64);
        acc[k] += __shfl_down(acc[k], 16, 64);
    }

    // ---- 16x16 transpose in wave-private LDS (same wave: no barrier) ----
    if (l < 16) {
        float4* pp = (float4*)&s_part[w][l][0];
        pp[0] = make_float4(acc[0],  acc[1],  acc[2],  acc[3]);
        pp[1] = make_float4(acc[4],  acc[5],  acc[6],  acc[7]);
        pp[2] = make_float4(acc[8],  acc[9],  acc[10], acc[11]);
        pp[3] = make_float4(acc[12], acc[13], acc[14], acc[15]);
    }
    if (l < 16) {
        float s = 0.f;
        #pragma unroll
        for (int r = 0; r < 16; ++r) s += s_part[w][r][l];
        sums[(size_t)b * 16 + l] = s;     // 16-lane coalesced store
    }
}

// ---------------------------------------------------------------------------
// Kernel 2: one thread per batch — fp32 Horn quaternion / 4x4 Jacobi (SIMT)
// ---------------------------------------------------------------------------
__global__ __launch_bounds__(BLK) void solve_kernel(
    const float* __restrict__ sums,   // (B, 16)
    float* __restrict__ Rt,           // (B, 12)
    int B)
{
    const int b = blockIdx.x * BLK + threadIdx.x;
    if (b >= B) return;

    float f[16];
    #pragma unroll
    for (int k = 0; k < 16; ++k) f[k] = sums[(size_t)b * 16 + k];

    const float W = f[0];
    const float invW = 1.0f / W;
    const float v1cx = f[1] * invW, v1cy = f[2] * invW, v1cz = f[3] * invW;
    const float v2cx = f[4] * invW, v2cy = f[5] * invW, v2cz = f[6] * invW;

    const float Sxx = f[7]  - W * v2cx * v1cx;
    const float Sxy = f[8]  - W * v2cx * v1cy;
    const float Sxz = f[9]  - W * v2cx * v1cz;
    const float Syx = f[10] - W * v2cy * v1cx;
    const float Syy = f[11] - W * v2cy * v1cy;
    const float Syz = f[12] - W * v2cy * v1cz;
    const float Szx = f[13] - W * v2cz * v1cx;
    const float Szy = f[14] - W * v2cz * v1cy;
    const float Szz = f[15] - W * v2cz * v1cz;

    float A[4][4];
    A[0][0] = Sxx + Syy + Szz;
    A[0][1] = Syz - Szy;  A[0][2] = Szx - Sxz;  A[0][3] = Sxy - Syx;
    A[1][1] = Sxx - Syy - Szz;
    A[1][2] = Sxy + Syx;  A[1][3] = Szx + Sxz;
    A[2][2] = -Sxx + Syy - Szz;
    A[2][3] = Syz + Szy;
    A[3][3] = -Sxx - Syy + Szz;
    A[1][0] = A[0][1]; A[2][0] = A[0][2]; A[3][0] = A[0][3];
    A[2][1] = A[1][2]; A[3][1] = A[1][3]; A[3][2] = A[2][3];

    float V[4][4] = {{1,0,0,0},{0,1,0,0},{0,0,1,0},{0,0,0,1}};

    const int prs[6][2] = {{0,1},{0,2},{0,3},{1,2},{1,3},{2,3}};
    for (int sweep = 0; sweep < 5; ++sweep) {
        #pragma unroll
        for (int r = 0; r < 6; ++r) {
            const int p = prs[r][0], q = prs[r][1];
            float apq = A[p][q];
            if (apq != 0.0f) {
                float tau = (A[q][q] - A[p][p]) / (2.0f * apq);
                float t = copysignf(1.0f, tau) /
                          (fabsf(tau) + sqrtf(1.0f + tau * tau));
                float c = rsqrtf(1.0f + t * t);
                float s = t * c;
                #pragma unroll
                for (int k = 0; k < 4; ++k) {
                    float a1 = A[p][k], a2 = A[q][k];
                    A[p][k] = c * a1 - s * a2;
                    A[q][k] = s * a1 + c * a2;
                }
                #pragma unroll
                for (int k = 0; k < 4; ++k) {
                    float a1 = A[k][p], a2 = A[k][q];
                    A[k][p] = c * a1 - s * a2;
                    A[k][q] = s * a1 + c * a2;
                }
                #pragma unroll
                for (int k = 0; k < 4; ++k) {
                    float a1 = V[k][p], a2 = V[k][q];
                    V[k][p] = c * a1 - s * a2;
                    V[k][q] = s * a1 + c * a2;
                }
            }
        }
    }

    int best = 0;
    #pragma unroll
    for (int i = 1; i < 4; ++i) if (A[i][i] > A[best][best]) best = i;
    const float q0 = V[0][best], qx = V[1][best], qy = V[2][best], qz = V[3][best];

    const float R00 = q0*q0 + qx*qx - qy*qy - qz*qz;
    const float R01 = 2.0f * (qx*qy - q0*qz);
    const float R02 = 2.0f * (qx*qz + q0*qy);
    const float R10 = 2.0f * (qx*qy + q0*qz);
    const float R11 = q0*q0 - qx*qx + qy*qy - qz*qz;
    const float R12 = 2.0f * (qy*qz - q0*qx);
    const float R20 = 2.0f * (qx*qz - q0*qy);
    const float R21 = 2.0f * (qy*qz + q0*qx);
    const float R22 = q0*q0 - qx*qx - qy*qy + qz*qz;

    float* o = Rt + (size_t)b * 12;
    o[0] = R00; o[1]  = R01; o[2]  = R02;
    o[3] = R10; o[4]  = R11; o[5]  = R12;
    o[6] = R20; o[7]  = R21; o[8]  = R22;
    o[9]  = v1cx - (R00 * v2cx + R01 * v2cy + R02 * v2cz);
    o[10] = v1cy - (R10 * v2cx + R11 * v2cy + R12 * v2cz);
    o[11] = v1cz - (R20 * v2cx + R21 * v2cy + R22 * v2cz);
}

// ---------------------------------------------------------------------------
// Kernel 3: apply — 4 points/thread. Reads xyz2 via dword-aligned float4
// from net_in (L3-hot after reduce), writes 3 FULL float4 per thread.
// No LDS, no barriers.
// ---------------------------------------------------------------------------
__global__ __launch_bounds__(BLK) void apply_kernel(
    const float* __restrict__ net_in,   // (B, 200, 13)
    const float* __restrict__ Rt,       // (B, 12)
    float* __restrict__ out,            // (B, 200, 3)
    int total)                          // B * 50
{
    const int g = blockIdx.x * BLK + threadIdx.x;   // 4-point group id
    if (g >= total) return;
    const int b = g / 50;
    const int q = g - b * 50;                       // quad index in batch

    const float* r = Rt + (size_t)b * 12;
    const float R00 = r[0], R01 = r[1], R02 = r[2];
    const float R10 = r[3], R11 = r[4], R12 = r[5];
    const float R20 = r[6], R21 = r[7], R22 = r[8];
    const float t0  = r[9], t1  = r[10], t2 = r[11];

    const float* base = net_in + (size_t)b * FPB + (q * 4) * NCH;
    float nx[4], ny[4], nz[4];
    #pragma unroll
    for (int i = 0; i < 4; ++i) {
        const f4u v = *(const f4u*)(base + i * NCH + 4);   // x2,y2,z2,(n1x)
        nx[i] = R00 * v.x + R01 * v.y + R02 * v.z + t0;
        ny[i] = R10 * v.x + R11 * v.y + R12 * v.z + t1;
        nz[i] = R20 * v.x + R21 * v.y + R22 * v.z + t2;
    }

    float4* p = (float4*)(out + (size_t)b * (NPTS * 3)) + q * 3;  // 16B aligned
    p[0] = make_float4(nx[0], ny[0], nz[0], nx[1]);
    p[1] = make_float4(ny[1], nz[1], nx[2], ny[2]);
    p[2] = make_float4(nz[2], nx[3], ny[3], nz[3]);
}

extern "C" void kernel_launch(void* const* d_in, const int* in_sizes, int n_in,
                              void* d_out, int out_size, void* d_ws, size_t ws_size,
                              hipStream_t stream) {
    const float* net_in  = (const float*)d_in[0];
    const float* shift_p = (const float*)d_in[1];
    const float* a_p     = (const float*)d_in[2];
    const float* b_p     = (const float*)d_in[3];
    float* out = (float*)d_out;

    const int B = in_sizes[0] / FPB;             // 8192

    float* sums = (float*)d_ws;                  // B * 16 floats
    float* Rt   = sums + (size_t)B * 16;         // B * 12 floats

    reduce_kernel<<<B / 4, BLK, 0, stream>>>(net_in, shift_p, a_p, b_p, sums);
    solve_kernel<<<(B + BLK - 1) / BLK, BLK, 0, stream>>>(sums, Rt, B);
    apply_kernel<<<(B * 50 + BLK - 1) / BLK, BLK, 0, stream>>>(net_in, Rt, out, B * 50);
}